// Round 1
// baseline (88.369 us; speedup 1.0000x reference)
//
#include <hip/hip_runtime.h>
#include <math.h>

#define CH 1
#define H 1024
#define NN 64
#define N_SSM 1024
#define SEQ_L 2048
#define TPB 256
#define LPT 8   // l-values per thread; SEQ_L / TPB == LPT

__global__ __launch_bounds__(TPB) void sskd_kernel(
    const float* __restrict__ C_ri, const float* __restrict__ log_dt,
    const float* __restrict__ B_ri, const float* __restrict__ inv_A_real,
    const float* __restrict__ A_imag, float* __restrict__ out)
{
    const int h   = blockIdx.x;
    const int tid = threadIdx.x;

    __shared__ float sCt_r[NN], sCt_i[NN], sLogr[NN], sThrev[NN], sDr[NN], sDi[NN];

    if (tid < NN) {
        const int n = tid;
        const float dt  = __expf(log_dt[h]);
        const float Ar  = -__expf(inv_A_real[h * NN + n]);
        const float Ai  = A_imag[h * NN + n];
        const float dtAr = Ar * dt, dtAi = Ai * dt;
        const float den_r = 1.0f - 0.5f * dtAr;
        const float den_i = -0.5f * dtAi;
        const float num_r = 1.0f + 0.5f * dtAr;
        const float num_i = 0.5f * dtAi;
        const float inv_den = 1.0f / (den_r * den_r + den_i * den_i);
        const float dA_r = (num_r * den_r + num_i * den_i) * inv_den;
        const float dA_i = (num_i * den_r - num_r * den_i) * inv_den;
        const int   bh = h % N_SSM;                       // rep==1 here, kept general
        const float Br = B_ri[(bh * NN + n) * 2 + 0];
        const float Bi = B_ri[(bh * NN + n) * 2 + 1];
        const float Cr = C_ri[(h * NN + n) * 2 + 0];
        const float Ci = C_ri[(h * NN + n) * 2 + 1];
        const float BCr = Br * Cr - Bi * Ci;
        const float BCi = Br * Ci + Bi * Cr;
        // Ct = B*C/den*dt ; fold the final 2*Re(...) factor of 2 in here
        const float sc = 2.0f * dt * inv_den;
        sCt_r[n] = (BCr * den_r + BCi * den_i) * sc;
        sCt_i[n] = (BCi * den_r - BCr * den_i) * sc;
        const float mag2 = dA_r * dA_r + dA_i * dA_i;     // |dA|^2 < 1
        sLogr[n]  = fmaxf(0.5f * __logf(mag2), -1.0e30f); // clamp: avoid -inf*0 NaN at l=0
        sThrev[n] = atan2f(dA_i, dA_r) * 0.15915494309189535f;  // arg(dA) in revolutions
        sDr[n] = dA_r;
        sDi[n] = dA_i;
    }
    __syncthreads();

    const float l0 = (float)(tid * LPT);
    float acc[LPT];
    #pragma unroll
    for (int k = 0; k < LPT; ++k) acc[k] = 0.0f;

    #pragma unroll 4
    for (int n = 0; n < NN; ++n) {
        const float ctr = sCt_r[n], cti = sCt_i[n];
        const float dr  = sDr[n],   di  = sDi[n];
        // base point: w = dA^l0 = exp(log|dA|*l0) * (cos(th*l0) + i sin(th*l0))
        const float e  = __expf(sLogr[n] * l0);
        float ph = sThrev[n] * l0;
        ph = (ph - floorf(ph)) * 6.283185307179586f;      // frac in revolutions -> radians
        float sn, cs;
        __sincosf(ph, &sn, &cs);
        float wr = e * cs, wi = e * sn;
        #pragma unroll
        for (int k = 0; k < LPT; ++k) {
            acc[k] = fmaf(ctr, wr, fmaf(-cti, wi, acc[k]));  // += Re(Ct * w) (2x folded)
            const float nwr = fmaf(wr, dr, -(wi * di));      // w *= dA
            const float nwi = fmaf(wr, di,  wi * dr);
            wr = nwr; wi = nwi;
        }
    }

    float4* o = (float4*)(out + (size_t)h * SEQ_L + tid * LPT);
    o[0] = make_float4(acc[0], acc[1], acc[2], acc[3]);
    o[1] = make_float4(acc[4], acc[5], acc[6], acc[7]);
}

extern "C" void kernel_launch(void* const* d_in, const int* in_sizes, int n_in,
                              void* d_out, int out_size, void* d_ws, size_t ws_size,
                              hipStream_t stream) {
    const float* C_ri       = (const float*)d_in[0];
    const float* log_dt     = (const float*)d_in[1];
    const float* B_ri       = (const float*)d_in[2];
    const float* inv_A_real = (const float*)d_in[3];
    const float* A_imag     = (const float*)d_in[4];
    float* out = (float*)d_out;

    sskd_kernel<<<dim3(H), dim3(TPB), 0, stream>>>(
        C_ri, log_dt, B_ri, inv_A_real, A_imag, out);
}

// Round 2
// 82.388 us; speedup vs baseline: 1.0726x; 1.0726x over previous
//
#include <hip/hip_runtime.h>
#include <math.h>

#define CH 1
#define H 1024
#define NN 64
#define N_SSM 1024
#define SEQ_L 2048
#define TPB 256
#define LPT 8   // l-values per thread; SEQ_L / TPB == LPT

__global__ __launch_bounds__(TPB) void sskd_kernel(
    const float* __restrict__ C_ri, const float* __restrict__ log_dt,
    const float* __restrict__ B_ri, const float* __restrict__ inv_A_real,
    const float* __restrict__ A_imag, float* __restrict__ out)
{
    const int h   = blockIdx.x;
    const int tid = threadIdx.x;

    // Per-n params: 2*Ct, 2*Ct*dA (for x1), recurrence coeffs p,q, and base exp/phase
    __shared__ float sCtr[NN], sCti[NN], sCdr[NN], sCdi[NN],
                     sP[NN], sQ[NN], sLogr[NN], sThrev[NN];

    if (tid < NN) {
        const int n = tid;
        const float dt  = __expf(log_dt[h]);
        const float Ar  = -__expf(inv_A_real[h * NN + n]);
        const float Ai  = A_imag[h * NN + n];
        const float dtAr = Ar * dt, dtAi = Ai * dt;
        const float den_r = 1.0f - 0.5f * dtAr;
        const float den_i = -0.5f * dtAi;
        const float num_r = 1.0f + 0.5f * dtAr;
        const float num_i = 0.5f * dtAi;
        const float inv_den = 1.0f / (den_r * den_r + den_i * den_i);
        const float dA_r = (num_r * den_r + num_i * den_i) * inv_den;
        const float dA_i = (num_i * den_r - num_r * den_i) * inv_den;
        const int   bh = h % N_SSM;                       // rep==1 here, kept general
        const float Br = B_ri[(bh * NN + n) * 2 + 0];
        const float Bi = B_ri[(bh * NN + n) * 2 + 1];
        const float Cr = C_ri[(h * NN + n) * 2 + 0];
        const float Ci = C_ri[(h * NN + n) * 2 + 1];
        const float BCr = Br * Cr - Bi * Ci;
        const float BCi = Br * Ci + Bi * Cr;
        // Ct = B*C/den*dt ; fold the final 2*Re(...) factor of 2 in here
        const float sc = 2.0f * dt * inv_den;
        const float ctr = (BCr * den_r + BCi * den_i) * sc;
        const float cti = (BCi * den_r - BCr * den_i) * sc;
        sCtr[n] = ctr;
        sCti[n] = cti;
        // ct * dA  (so x1 = Re((ct*dA)*w0) needs only 2 ops)
        sCdr[n] = ctr * dA_r - cti * dA_i;
        sCdi[n] = ctr * dA_i + cti * dA_r;
        // 2nd-order real recurrence: x_l = p*x_{l-1} - q*x_{l-2}
        sP[n] = 2.0f * dA_r;
        sQ[n] = dA_r * dA_r + dA_i * dA_i;                // |dA|^2 < 1
        sLogr[n]  = fmaxf(0.5f * __logf(sQ[n]), -1.0e30f);
        sThrev[n] = atan2f(dA_i, dA_r) * 0.15915494309189535f;  // arg in revolutions
    }
    __syncthreads();

    const float l0 = (float)(tid * LPT);
    float acc[LPT];
    #pragma unroll
    for (int k = 0; k < LPT; ++k) acc[k] = 0.0f;

    #pragma unroll 4
    for (int n = 0; n < NN; ++n) {
        // base point: w0 = dA^l0 via exp + sincos (revolution phase keeps |arg| small)
        const float e  = __expf(sLogr[n] * l0);
        float ph = sThrev[n] * l0;
        ph -= floorf(ph);
        float sn, cs;
        __sincosf(ph * 6.283185307179586f, &sn, &cs);
        const float wr = e * cs, wi = e * sn;
        float x2 = sCtr[n] * wr - sCti[n] * wi;   // x(l0)   = Re(2Ct * w0)
        float x1 = sCdr[n] * wr - sCdi[n] * wi;   // x(l0+1) = Re(2Ct*dA * w0)
        acc[0] += x2;
        acc[1] += x1;
        const float p = sP[n], q = sQ[n];
        #pragma unroll
        for (int k = 2; k < LPT; ++k) {
            const float xn = fmaf(p, x1, -(q * x2));
            acc[k] += xn;
            x2 = x1;
            x1 = xn;
        }
    }

    float4* o = (float4*)(out + (size_t)h * SEQ_L + tid * LPT);
    o[0] = make_float4(acc[0], acc[1], acc[2], acc[3]);
    o[1] = make_float4(acc[4], acc[5], acc[6], acc[7]);
}

extern "C" void kernel_launch(void* const* d_in, const int* in_sizes, int n_in,
                              void* d_out, int out_size, void* d_ws, size_t ws_size,
                              hipStream_t stream) {
    const float* C_ri       = (const float*)d_in[0];
    const float* log_dt     = (const float*)d_in[1];
    const float* B_ri       = (const float*)d_in[2];
    const float* inv_A_real = (const float*)d_in[3];
    const float* A_imag     = (const float*)d_in[4];
    float* out = (float*)d_out;

    sskd_kernel<<<dim3(H), dim3(TPB), 0, stream>>>(
        C_ri, log_dt, B_ri, inv_A_real, A_imag, out);
}

// Round 3
// 78.952 us; speedup vs baseline: 1.1193x; 1.0435x over previous
//
#include <hip/hip_runtime.h>
#include <math.h>

#define CH 1
#define H 1024
#define NN 64
#define N_SSM 1024
#define SEQ_L 2048
#define TPB 256
#define LPT 8   // l-values per thread; SEQ_L / TPB == LPT

typedef float v2f __attribute__((ext_vector_type(2)));

__global__ __launch_bounds__(TPB) void sskd_kernel(
    const float* __restrict__ C_ri, const float* __restrict__ log_dt,
    const float* __restrict__ B_ri, const float* __restrict__ inv_A_real,
    const float* __restrict__ A_imag, float* __restrict__ out)
{
    const int h   = blockIdx.x;
    const int tid = threadIdx.x;

    // Per-n params, pair-adjacent so the main loop reads them as float2 (ds_read_b64)
    __shared__ __align__(8) float sCtr[NN], sCti[NN], sCdr[NN], sCdi[NN],
                                  sP[NN], sQ[NN], sLogr[NN], sThrev[NN];

    if (tid < NN) {
        const int n = tid;
        const float dt  = __expf(log_dt[h]);
        const float Ar  = -__expf(inv_A_real[h * NN + n]);
        const float Ai  = A_imag[h * NN + n];
        const float dtAr = Ar * dt, dtAi = Ai * dt;
        const float den_r = 1.0f - 0.5f * dtAr;
        const float den_i = -0.5f * dtAi;
        const float num_r = 1.0f + 0.5f * dtAr;
        const float num_i = 0.5f * dtAi;
        const float inv_den = 1.0f / (den_r * den_r + den_i * den_i);
        const float dA_r = (num_r * den_r + num_i * den_i) * inv_den;
        const float dA_i = (num_i * den_r - num_r * den_i) * inv_den;
        const int   bh = h % N_SSM;                       // rep==1 here, kept general
        const float Br = B_ri[(bh * NN + n) * 2 + 0];
        const float Bi = B_ri[(bh * NN + n) * 2 + 1];
        const float Cr = C_ri[(h * NN + n) * 2 + 0];
        const float Ci = C_ri[(h * NN + n) * 2 + 1];
        const float BCr = Br * Cr - Bi * Ci;
        const float BCi = Br * Ci + Bi * Cr;
        // Ct = B*C/den*dt ; fold the final 2*Re(...) factor of 2 in here
        const float sc = 2.0f * dt * inv_den;
        const float ctr = (BCr * den_r + BCi * den_i) * sc;
        const float cti = (BCi * den_r - BCr * den_i) * sc;
        sCtr[n] = ctr;
        sCti[n] = cti;
        // ct * dA  (so x1 = Re((ct*dA)*w0) needs only a packed mul+fma)
        sCdr[n] = ctr * dA_r - cti * dA_i;
        sCdi[n] = ctr * dA_i + cti * dA_r;
        // 2nd-order real recurrence: x_l = p*x_{l-1} - q*x_{l-2}
        const float q = dA_r * dA_r + dA_i * dA_i;        // |dA|^2 < 1
        sP[n] = 2.0f * dA_r;
        sQ[n] = q;
        sLogr[n]  = fmaxf(0.5f * __logf(q), -1.0e30f);
        sThrev[n] = atan2f(dA_i, dA_r) * 0.15915494309189535f;  // arg in revolutions
    }
    __syncthreads();

    const float l0 = (float)(tid * LPT);
    v2f acc[LPT];
    #pragma unroll
    for (int k = 0; k < LPT; ++k) acc[k] = (v2f)(0.0f);

    // Two n's per iteration, packed into float2 lanes -> v_pk_* f32 ops
    #pragma unroll 2
    for (int m = 0; m < NN / 2; ++m) {
        const v2f logr  = *(const v2f*)&sLogr[2 * m];
        const v2f threv = *(const v2f*)&sThrev[2 * m];
        v2f e;
        e.x = __expf(logr.x * l0);
        e.y = __expf(logr.y * l0);
        v2f ph = threv * l0;
        ph.x -= floorf(ph.x);
        ph.y -= floorf(ph.y);
        float snx, csx, sny, csy;
        __sincosf(ph.x * 6.283185307179586f, &snx, &csx);
        __sincosf(ph.y * 6.283185307179586f, &sny, &csy);
        v2f wr, wi;
        wr.x = e.x * csx; wr.y = e.y * csy;
        wi.x = e.x * snx; wi.y = e.y * sny;

        const v2f ctr = *(const v2f*)&sCtr[2 * m];
        const v2f cti = *(const v2f*)&sCti[2 * m];
        const v2f cdr = *(const v2f*)&sCdr[2 * m];
        const v2f cdi = *(const v2f*)&sCdi[2 * m];
        const v2f p   = *(const v2f*)&sP[2 * m];
        const v2f q   = *(const v2f*)&sQ[2 * m];

        v2f x2 = ctr * wr - cti * wi;   // x(l0)   = Re(2Ct * w0), per packed n
        v2f x1 = cdr * wr - cdi * wi;   // x(l0+1) = Re(2Ct*dA * w0)
        acc[0] += x2;
        acc[1] += x1;
        #pragma unroll
        for (int k = 2; k < LPT; ++k) {
            const v2f xn = p * x1 - q * x2;   // contracts to v_pk_mul + v_pk_fma
            acc[k] += xn;
            x2 = x1;
            x1 = xn;
        }
    }

    float4 o0, o1;
    o0.x = acc[0].x + acc[0].y;
    o0.y = acc[1].x + acc[1].y;
    o0.z = acc[2].x + acc[2].y;
    o0.w = acc[3].x + acc[3].y;
    o1.x = acc[4].x + acc[4].y;
    o1.y = acc[5].x + acc[5].y;
    o1.z = acc[6].x + acc[6].y;
    o1.w = acc[7].x + acc[7].y;
    float4* o = (float4*)(out + (size_t)h * SEQ_L + tid * LPT);
    o[0] = o0;
    o[1] = o1;
}

extern "C" void kernel_launch(void* const* d_in, const int* in_sizes, int n_in,
                              void* d_out, int out_size, void* d_ws, size_t ws_size,
                              hipStream_t stream) {
    const float* C_ri       = (const float*)d_in[0];
    const float* log_dt     = (const float*)d_in[1];
    const float* B_ri       = (const float*)d_in[2];
    const float* inv_A_real = (const float*)d_in[3];
    const float* A_imag     = (const float*)d_in[4];
    float* out = (float*)d_out;

    sskd_kernel<<<dim3(H), dim3(TPB), 0, stream>>>(
        C_ri, log_dt, B_ri, inv_A_real, A_imag, out);
}